// Round 14
// baseline (1219.568 us; speedup 1.0000x reference)
//
#include <hip/hip_runtime.h>
#include <hip/hip_bf16.h>
#include <cstdint>

#define DEV __device__ __forceinline__

typedef __bf16 bf16_t;
typedef bf16_t bf16x8 __attribute__((ext_vector_type(8)));
typedef float  f32x4  __attribute__((ext_vector_type(4)));

static constexpr int B_ = 8, T_ = 1024, S_ = 1024, D_ = 512, H_ = 8, F_ = 2048;

typedef const __attribute__((address_space(1))) void* gas_ptr;
typedef __attribute__((address_space(3))) void* las_ptr;

DEV void gload_lds16(const void* g, void* l) {
  __builtin_amdgcn_global_load_lds((gas_ptr)g, (las_ptr)l, 16, 0, 0);
}

// ---------------------------------------------------------------------------
// bf16 GEMM:  C[z] = A[z] (M x K, row-major) * BT[z]^T  (BT is N x K row-major)
// R10-proven config: BM = MI*32 (MI=2 -> 64), BN = 128 fixed. 48 KB LDS double
// buffer, 3 blocks/CU. Counted-vmcnt (steady vmcnt(6): next tile in flight,
// never 0 mid-loop) + raw barriers + T2 XOR-swizzle (pre-swizzled global
// source + swizzled ds_read) + T5 setprio + T1 bijective XCD swizzle.
// EPI 0:+bias | 1:+bias,relu | 2:*scale+pad+subsq | 3: accumulate fp32
// causal: 0=none, 2=fully-masked blocks write NOTHING (softmax zero-fill)
// kcap: causal K-limit (rows m0.. need K < m0+BM only)
// biasRow: bias indexed by output ROW (for direct-V^T projection)
// ---------------------------------------------------------------------------
template<typename OutT, int EPI, int MI>
__global__ __launch_bounds__(256, (MI == 2) ? 3 : 2) void gemm_bt(
    const bf16_t* __restrict__ A,  int64_t aH, int64_t aB, int lda,
    const bf16_t* __restrict__ BT, int64_t bH, int64_t bB, int ldb,
    OutT* __restrict__ C,          int64_t cH, int64_t cB, int ldo,
    int K, int ZB,
    const float* __restrict__ bias, int64_t biasH, int64_t biasB,
    float scale,
    const float* __restrict__ pad, int64_t padB,
    const float* __restrict__ subsq, int subsq_ld, int causal,
    int initC, int kcap, int biasRow)
{
  constexpr int BM = MI * 32;          // 64 or 128

  // ---- bijective XCD-chunked swizzle over the flattened grid (m204)
  const unsigned gx = gridDim.x, gy = gridDim.y;
  const unsigned nwg = gx * gy * gridDim.z;
  const unsigned orig = (blockIdx.z * gy + blockIdx.y) * gx + blockIdx.x;
  const unsigned q8 = nwg >> 3, r8 = nwg & 7;
  const unsigned xcd = orig & 7, cidx = orig >> 3;
  const unsigned swz = (xcd < r8 ? xcd * (q8 + 1)
                                 : r8 * (q8 + 1) + (xcd - r8) * q8) + cidx;
  const unsigned bz = swz / (gx * gy);
  const unsigned rm = swz - bz * gx * gy;
  const unsigned by = rm / gx;
  const unsigned bx = rm - by * gx;

  const int z  = bz;
  const int zh = z / ZB, zb = z - zh * ZB;
  A  += zh * aH + zb * aB;
  BT += zh * bH + zb * bB;
  C  += zh * cH + zb * cB;
  const int m0 = by * BM;
  const int n0 = bx << 7;

  // fully-masked causal block
  const bool skip = (EPI == 2) && causal && (n0 >= m0 + BM);
  if (skip && causal == 2) return;     // write nothing; nobody reads it

  __shared__ __align__(16) bf16_t As[2][BM * 64];
  __shared__ __align__(16) bf16_t Bs[2][128 * 64];

  const int tid  = threadIdx.x;
  const int lane = tid & 63;
  const int wr   = tid >> 7;          // wave row (0..1)
  const int wc   = (tid >> 6) & 1;    // wave col (0..1)

  f32x4 acc[MI][4] = {};

  int Klim = K;
  if (kcap) { const int lim = m0 + BM; Klim = lim < K ? lim : K; }

  // stage with pre-swizzled global column: LDS slot (row, s) <- global granule
  // (row, s ^ (row&7)); reader XORs the same way -> conflict-free ds_read_b128
  auto stage = [&](int buf, int kb) {
    #pragma unroll
    for (int i = 0; i < MI; ++i) {     // A: BM*64 elems = MI chunks/thread
      const int c = i * 256 + tid;
      const int row = c >> 3;
      const int col = (((c & 7) ^ (row & 7)) << 3);
      gload_lds16(A + (int64_t)(m0 + row) * lda + kb + col, &As[buf][c * 8]);
    }
    #pragma unroll
    for (int i = 0; i < 4; ++i) {      // B: 128*64 elems = 4 chunks/thread
      const int c = i * 256 + tid;
      const int row = c >> 3;
      const int col = (((c & 7) ^ (row & 7)) << 3);
      gload_lds16(BT + (int64_t)(n0 + row) * ldb + kb + col, &Bs[buf][c * 8]);
    }
  };

  if (!skip) {
    const int NT = Klim >> 6;
    stage(0, 0);
    if (NT > 1) stage(1, 64);
    const int hi = lane >> 4, r7 = lane & 7;
    for (int t = 0; t < NT; ++t) {
      // wait tile t complete; tile t+1 (MI+4 loads/thread) stays in flight
      if (t + 1 < NT) {
        if constexpr (MI == 2) asm volatile("s_waitcnt vmcnt(6)" ::: "memory");
        else                   asm volatile("s_waitcnt vmcnt(8)" ::: "memory");
      } else {
        asm volatile("s_waitcnt vmcnt(0)" ::: "memory");
      }
      __builtin_amdgcn_s_barrier();              // raw: no implicit drain
      __builtin_amdgcn_sched_barrier(0);
      const int cur = t & 1;
      // pre-read ALL fragments of tile t (buffer gets overwritten below)
      bf16x8 af[MI][2], bq[4][2];
      #pragma unroll
      for (int ks = 0; ks < 2; ++ks) {
        #pragma unroll
        for (int i = 0; i < MI; ++i)
          af[i][ks] = *(const bf16x8*)&As[cur][(wr * (MI * 16) + i * 16 + (lane & 15)) * 64 + (((ks * 4 + hi) ^ r7) << 3)];
        #pragma unroll
        for (int i = 0; i < 4; ++i)
          bq[i][ks] = *(const bf16x8*)&Bs[cur][(wc * 64 + i * 16 + (lane & 15)) * 64 + (((ks * 4 + hi) ^ r7) << 3)];
      }
      asm volatile("s_waitcnt lgkmcnt(0)" ::: "memory");
      __builtin_amdgcn_sched_barrier(0);
      __builtin_amdgcn_s_barrier();              // all waves done reading buf
      if (t + 2 < NT) stage(cur, (t + 2) << 6);  // restage freed buffer early
      __builtin_amdgcn_sched_barrier(0);         // keep MFMAs after stage issue
      __builtin_amdgcn_s_setprio(1);
      #pragma unroll
      for (int ks = 0; ks < 2; ++ks)
        #pragma unroll
        for (int mi = 0; mi < MI; ++mi)
          #pragma unroll
          for (int ni = 0; ni < 4; ++ni)
            acc[mi][ni] = __builtin_amdgcn_mfma_f32_16x16x32_bf16(af[mi][ks], bq[ni][ks], acc[mi][ni], 0, 0, 0);
      __builtin_amdgcn_s_setprio(0);
    }
  }

  // epilogue; C/D frag layout: col = lane&15, row = 4*(lane>>4)+r
  const float* bz_ = (EPI != 2 && bias) ? bias + zh * biasH + zb * biasB : nullptr;
  const float* pz  = (EPI == 2 && pad)  ? pad + zb * padB : nullptr;
  #pragma unroll
  for (int ni = 0; ni < 4; ++ni) {
    const int col = n0 + wc * 64 + ni * 16 + (lane & 15);
    const float baddC = (bz_ && !biasRow) ? bz_[col] : 0.f;
    const float pv    = pz ? pz[col] : 0.f;
    #pragma unroll
    for (int mi = 0; mi < MI; ++mi) {
      const int rowb = m0 + wr * (MI * 16) + mi * 16 + ((lane >> 4) << 2);
      #pragma unroll
      for (int r = 0; r < 4; ++r) {
        const int row = rowb + r;
        const int64_t idx = (int64_t)row * ldo + col;
        float v = acc[mi][ni][r];
        if (EPI == 2) {
          v = v * scale + pv;
          if (subsq) v += subsq[(int64_t)row * subsq_ld + col];
        } else if (EPI == 3) {
          v += initC ? baddC : (float)C[idx];
        } else {
          v += biasRow ? (bz_ ? bz_[row] : 0.f) : baddC;
          if (EPI == 1) v = fmaxf(v, 0.f);
        }
        if constexpr (sizeof(OutT) == 2) C[idx] = (OutT)v;
        else                             C[idx] = v;
      }
    }
  }
}

// ---------------------------------------------------------------------------
// In-place row softmax over 1024 bf16 logits. One block (256 thr) per row.
// CAUSAL=1: row length = (blockIdx % T)+1; reads only the causal prefix,
// zero-fills up to the next multiple of 64 (what PV's kcap reads).
// ---------------------------------------------------------------------------
template<int CAUSAL>
__global__ __launch_bounds__(256) void softmax1024b(bf16_t* __restrict__ P)
{
  const int64_t row = blockIdx.x;
  const int len = CAUSAL ? (int)(row % T_) + 1 : 1024;
  const int tid = threadIdx.x;
  const int j4 = tid << 2;
  float v0 = -3e38f, v1 = -3e38f, v2 = -3e38f, v3 = -3e38f;
  if (j4 < len) {
    union { bf16_t b[4]; uint2 u; } in;
    in.u = ((const uint2*)(P + row * 1024))[tid];
    v0 = (float)in.b[0];
    if (j4 + 1 < len) v1 = (float)in.b[1];
    if (j4 + 2 < len) v2 = (float)in.b[2];
    if (j4 + 3 < len) v3 = (float)in.b[3];
  }
  float m = fmaxf(fmaxf(v0, v1), fmaxf(v2, v3));
  #pragma unroll
  for (int off = 32; off; off >>= 1) m = fmaxf(m, __shfl_xor(m, off));
  __shared__ float red[8];
  if ((tid & 63) == 0) red[tid >> 6] = m;
  __syncthreads();
  m = fmaxf(fmaxf(red[0], red[1]), fmaxf(red[2], red[3]));
  const float e0 = (j4     < len) ? __expf(v0 - m) : 0.f;
  const float e1 = (j4 + 1 < len) ? __expf(v1 - m) : 0.f;
  const float e2 = (j4 + 2 < len) ? __expf(v2 - m) : 0.f;
  const float e3 = (j4 + 3 < len) ? __expf(v3 - m) : 0.f;
  float s = e0 + e1 + e2 + e3;
  #pragma unroll
  for (int off = 32; off; off >>= 1) s += __shfl_xor(s, off);
  if ((tid & 63) == 0) red[4 + (tid >> 6)] = s;
  __syncthreads();
  const float inv = 1.f / (red[4] + red[5] + red[6] + red[7]);
  const int lenc = CAUSAL ? ((len + 63) & ~63) : 1024;  // PV reads < ceil64(len)
  if (j4 < lenc) {
    union { bf16_t b[4]; uint2 u; } o;
    o.b[0] = (bf16_t)(e0 * inv); o.b[1] = (bf16_t)(e1 * inv);
    o.b[2] = (bf16_t)(e2 * inv); o.b[3] = (bf16_t)(e3 * inv);
    ((uint2*)(P + row * 1024))[tid] = o.u;
  }
}

// ---------------------------------------------------------------------------
// y = LayerNorm(a + r) * g + b ; yf fp32 (may alias a or r: element-local),
// yb bf16 (nullable). D=512, block 128.
// ---------------------------------------------------------------------------
__global__ __launch_bounds__(128) void add_ln512(
    const float* __restrict__ a, const float* __restrict__ r,
    const float* __restrict__ g, const float* __restrict__ be,
    float* __restrict__ yf, bf16_t* __restrict__ yb)
{
  const int64_t row = blockIdx.x;
  const int tid = threadIdx.x;
  const float4 va = ((const float4*)(a + row * 512))[tid];
  const float4 vr = ((const float4*)(r + row * 512))[tid];
  const float x0 = va.x + vr.x, x1 = va.y + vr.y, x2 = va.z + vr.z, x3 = va.w + vr.w;
  float s = x0 + x1 + x2 + x3;
  float q = x0 * x0 + x1 * x1 + x2 * x2 + x3 * x3;
  #pragma unroll
  for (int off = 32; off; off >>= 1) { s += __shfl_xor(s, off); q += __shfl_xor(q, off); }
  __shared__ float red[4];
  if ((tid & 63) == 0) { red[tid >> 6] = s; red[2 + (tid >> 6)] = q; }
  __syncthreads();
  s = red[0] + red[1]; q = red[2] + red[3];
  const float mean = s * (1.f / 512.f);
  const float var  = q * (1.f / 512.f) - mean * mean;
  const float rstd = rsqrtf(var + 1e-5f);
  const float4 g4 = ((const float4*)g)[tid];
  const float4 b4 = ((const float4*)be)[tid];
  const float y0 = (x0 - mean) * rstd * g4.x + b4.x;
  const float y1 = (x1 - mean) * rstd * g4.y + b4.y;
  const float y2 = (x2 - mean) * rstd * g4.z + b4.z;
  const float y3 = (x3 - mean) * rstd * g4.w + b4.w;
  float4 o; o.x = y0; o.y = y1; o.z = y2; o.w = y3;
  ((float4*)(yf + row * 512))[tid] = o;
  if (yb) {
    union { bf16_t b[4]; uint2 u; } ob;
    ob.b[0] = (bf16_t)y0; ob.b[1] = (bf16_t)y1; ob.b[2] = (bf16_t)y2; ob.b[3] = (bf16_t)y3;
    ((uint2*)(yb + row * 512))[tid] = ob.u;
  }
}

// ---------------------------------------------------------------------------
// Transpose + cast: src [z][R][C] (InT) -> dst [z][C][R] (bf16)
// ---------------------------------------------------------------------------
template<typename InT>
__global__ __launch_bounds__(256) void tcast(
    const InT* __restrict__ src, bf16_t* __restrict__ dst, int R, int C)
{
  __shared__ float t[32][33];
  const int64_t zo = (int64_t)blockIdx.z * R * C;
  const int c0 = blockIdx.x << 5, r0 = blockIdx.y << 5;
  const int tx = threadIdx.x & 31, ty = threadIdx.x >> 5;
  #pragma unroll
  for (int i = 0; i < 32; i += 8)
    t[ty + i][tx] = (float)src[zo + (int64_t)(r0 + ty + i) * C + c0 + tx];
  __syncthreads();
  #pragma unroll
  for (int i = 0; i < 32; i += 8)
    dst[zo + (int64_t)(c0 + ty + i) * R + r0 + tx] = (bf16_t)t[tx][ty + i];
}

__global__ __launch_bounds__(256) void castf2b(
    const float* __restrict__ s, bf16_t* __restrict__ d, int n4)
{
  const int i = blockIdx.x * 256 + threadIdx.x;
  if (i >= n4) return;
  const float4 v = ((const float4*)s)[i];
  union { bf16_t b[4]; uint2 u; } o;
  o.b[0] = (bf16_t)v.x; o.b[1] = (bf16_t)v.y; o.b[2] = (bf16_t)v.z; o.b[3] = (bf16_t)v.w;
  ((uint2*)d)[i] = o.u;
}

__global__ __launch_bounds__(256) void pack3(
    const float* __restrict__ a, const float* __restrict__ b,
    const float* __restrict__ c, float* __restrict__ d, int n)
{
  const int i = blockIdx.x * 256 + threadIdx.x;
  if (i < n) { d[i] = a[i]; d[n + i] = b[i]; d[2 * n + i] = c[i]; }
}

// ---------------------------------------------------------------------------
extern "C" void kernel_launch(void* const* d_in, const int* in_sizes, int n_in,
                              void* d_out, int out_size, void* d_ws, size_t ws_size,
                              hipStream_t stream)
{
  const float* x       = (const float*)d_in[0];
  const float* src_pad = (const float*)d_in[1];
  const float* tgt_pad = (const float*)d_in[3];
  const float* tgt_sub = (const float*)d_in[4];
  const float* mk      = (const float*)d_in[5];
  const float* mv      = (const float*)d_in[6];
  const float* Wq  = (const float*)d_in[7];
  const float* bq  = (const float*)d_in[8];
  const float* Wk  = (const float*)d_in[9];
  const float* bk  = (const float*)d_in[10];
  const float* Wv  = (const float*)d_in[11];
  const float* bv  = (const float*)d_in[12];
  const float* Wo  = (const float*)d_in[13];
  const float* bo  = (const float*)d_in[14];
  const float* Wqm = (const float*)d_in[15];
  const float* bqm = (const float*)d_in[16];
  const float* Wom = (const float*)d_in[17];
  const float* bom = (const float*)d_in[18];
  const float* W1  = (const float*)d_in[19];
  const float* b1  = (const float*)d_in[20];
  const float* W2  = (const float*)d_in[21];
  const float* b2  = (const float*)d_in[22];
  const float* g1  = (const float*)d_in[23];
  const float* be1 = (const float*)d_in[24];
  const float* g2  = (const float*)d_in[25];
  const float* be2 = (const float*)d_in[26];
  const float* g3  = (const float*)d_in[27];
  const float* be3 = (const float*)d_in[28];
  float* outf = (float*)d_out;   // fp32 projection target / final out

  constexpr int64_t BTD = (int64_t)B_ * T_ * D_;
  constexpr int64_t BTS = (int64_t)B_ * T_ * S_;
  constexpr int64_t DD  = (int64_t)D_ * D_;
  const int M8 = B_ * T_;

  char* p = (char*)d_ws;
  auto alloc = [&](int64_t bytes) -> void* {
    char* r = p; p += (bytes + 255) & ~(int64_t)255; return (void*)r;
  };
  bf16_t* WTqkv = (bf16_t*)alloc(3 * H_ * DD * 2);            // [3][H][D][D]
  bf16_t* WoT   = (bf16_t*)alloc((int64_t)D_ * H_ * D_ * 2);
  bf16_t* WqmT  = (bf16_t*)alloc(H_ * DD * 2);
  bf16_t* WomT  = (bf16_t*)alloc((int64_t)D_ * H_ * D_ * 2);
  bf16_t* W1T   = (bf16_t*)alloc((int64_t)F_ * D_ * 2);
  bf16_t* W2T   = (bf16_t*)alloc((int64_t)D_ * F_ * 2);
  float*  bqkv  = (float*)alloc(3 * H_ * D_ * 4);
  bf16_t* actb  = (bf16_t*)alloc(BTD * 2);
  bf16_t* mkb   = (bf16_t*)alloc(BTD * 2);
  bf16_t* mvT   = (bf16_t*)alloc(BTD * 2);
  float*  x1f   = (float*)alloc(BTD * 4);

  const int64_t remain = (int64_t)ws_size - (int64_t)(p - (char*)d_ws);
  // per head: Q,K (2 slots) + vt + logit
  const int64_t perG   = 2 * BTD * 2 + BTD * 2 + BTS * 2;
  const int64_t hoCat  = (int64_t)B_ * T_ * H_ * D_ * 2;
  int G = 0;
  for (int g = 8; g >= 1; g >>= 1)
    if (remain >= hoCat + (int64_t)g * perG + (4 << 20)) { G = g; break; }
  const int64_t needB = 3 * BTD * 2 + BTD * 2 + BTS * 2 + BTD * 2 + (1 << 20);
  if (G == 0 && remain < needB) return;

  const float scale = 1.0f / sqrtf((float)D_);
  dim3 blk(256);

  castf2b<<<dim3((unsigned)(BTD / 4 / 256)), blk, 0, stream>>>(x, actb, (int)(BTD / 4));
  castf2b<<<dim3((unsigned)(BTD / 4 / 256)), blk, 0, stream>>>(mk, mkb, (int)(BTD / 4));
  tcast<float><<<dim3(D_ / 32, S_ / 32, B_), blk, 0, stream>>>(mv, mvT, S_, D_);
  tcast<float><<<dim3(D_ / 32, D_ / 32, H_), blk, 0, stream>>>(Wq, WTqkv, D_, D_);
  tcast<float><<<dim3(D_ / 32, D_ / 32, H_), blk, 0, stream>>>(Wk, WTqkv + H_ * DD, D_, D_);
  tcast<float><<<dim3(D_ / 32, D_ / 32, H_), blk, 0, stream>>>(Wv, WTqkv + 2 * H_ * DD, D_, D_);
  tcast<float><<<dim3(D_ / 32, (H_ * D_) / 32, 1), blk, 0, stream>>>(Wo, WoT, H_ * D_, D_);
  tcast<float><<<dim3(D_ / 32, D_ / 32, H_), blk, 0, stream>>>(Wqm, WqmT, D_, D_);
  tcast<float><<<dim3(D_ / 32, (H_ * D_) / 32, 1), blk, 0, stream>>>(Wom, WomT, H_ * D_, D_);
  tcast<float><<<dim3(F_ / 32, D_ / 32, 1), blk, 0, stream>>>(W1, W1T, D_, F_);
  tcast<float><<<dim3(D_ / 32, F_ / 32, 1), blk, 0, stream>>>(W2, W2T, F_, D_);
  pack3<<<dim3((H_ * D_ + 255) / 256), blk, 0, stream>>>(bq, bk, bv, bqkv, H_ * D_);

  bf16_t* ffh = nullptr;

  if (G > 0) {
    // =========== Path A: head-group batching, direct-V^T ===========
    bf16_t* hoAll = (bf16_t*)alloc(hoCat);                    // [B][T][H*D]
    bf16_t* qkv   = (bf16_t*)alloc(2 * G * BTD * 2);          // [2][G][B][T][D] (Q,K)
    bf16_t* vt    = (bf16_t*)alloc((int64_t)G * BTD * 2);     // [G][B][D][T]
    bf16_t* logit = (bf16_t*)alloc((int64_t)G * BTS * 2);     // [G][B][T][S]
    ffh = qkv;  // qkv(2G)+vt(G)+logit >= 32 MiB for all G>=1 (FFN runs after attn)

    for (int h0 = 0; h0 < H_; h0 += G) {
      // Q,K projections (z = qk*G + g)
      gemm_bt<bf16_t, 0, 2><<<dim3(D_ / 128, M8 / 64, 2 * G), blk, 0, stream>>>(
          actb, 0, 0, D_,
          WTqkv + (int64_t)h0 * DD, (int64_t)H_ * DD, DD, D_,
          qkv, (int64_t)G * BTD, BTD, D_,
          D_, G,
          bqkv + h0 * D_, (int64_t)H_ * D_, D_,
          1.f, nullptr, 0, nullptr, 0, 0, 0, 0, 0);
      // V^T direct: vt[g][b][e][t] = sum_d WvT[h][e][d] * x[b][t][d] + bv[e]
      gemm_bt<bf16_t, 0, 2><<<dim3(T_ / 128, D_ / 64, G * B_), blk, 0, stream>>>(
          WTqkv + (int64_t)(2 * H_ + h0) * DD, DD, 0, D_,
          actb, 0, (int64_t)T_ * D_, D_,
          vt, (int64_t)B_ * D_ * T_, (int64_t)D_ * T_, T_,
          D_, B_,
          bqkv + (2 * H_ + h0) * D_, D_, 0,
          1.f, nullptr, 0, nullptr, 0, 0, 0, 0, /*biasRow=*/1);
      // logits = q k^T * scale + pad + causal (z = g*B + b)
      gemm_bt<bf16_t, 2, 2><<<dim3(S_ / 128, T_ / 64, G * B_), blk, 0, stream>>>(
          qkv, BTD, (int64_t)T_ * D_, D_,
          qkv + (int64_t)G * BTD, BTD, (int64_t)T_ * D_, D_,
          logit, BTS, (int64_t)T_ * S_, S_,
          D_, B_,
          nullptr, 0, 0,
          scale, tgt_pad, T_, tgt_sub, S_, /*causal=*/2, 0, 0, 0);
      softmax1024b<1><<<dim3((unsigned)(G * B_ * T_)), blk, 0, stream>>>(logit);
      gemm_bt<bf16_t, 0, 2><<<dim3(D_ / 128, T_ / 64, G * B_), blk, 0, stream>>>(
          logit, BTS, (int64_t)T_ * S_, S_,
          vt, (int64_t)B_ * D_ * T_, (int64_t)D_ * T_, T_,
          hoAll + (int64_t)h0 * D_, D_, (int64_t)T_ * H_ * D_, H_ * D_,
          S_, B_,
          nullptr, 0, 0, 1.f, nullptr, 0, nullptr, 0, 0, 0, /*kcap=*/1, 0);
    }
    gemm_bt<float, 0, 2><<<dim3(D_ / 128, M8 / 64, 1), blk, 0, stream>>>(
        hoAll, 0, 0, H_ * D_, WoT, 0, 0, H_ * D_, outf, 0, 0, D_,
        H_ * D_, 1, bo, 0, 0, 1.f, nullptr, 0, nullptr, 0, 0, 0, 0, 0);
    add_ln512<<<dim3(M8), dim3(128), 0, stream>>>(outf, x, g1, be1, x1f, actb);

    for (int h0 = 0; h0 < H_; h0 += G) {
      gemm_bt<bf16_t, 0, 2><<<dim3(D_ / 128, M8 / 64, G), blk, 0, stream>>>(
          actb, 0, 0, D_,
          WqmT + (int64_t)h0 * DD, 0, DD, D_,
          qkv, 0, BTD, D_,
          D_, G,
          bqm + h0 * D_, 0, D_,
          1.f, nullptr, 0, nullptr, 0, 0, 0, 0, 0);
      gemm_bt<bf16_t, 2, 2><<<dim3(S_ / 128, T_ / 64, G * B_), blk, 0, stream>>>(
          qkv, BTD, (int64_t)T_ * D_, D_,
          mkb, 0, (int64_t)S_ * D_, D_,
          logit, BTS, (int64_t)T_ * S_, S_,
          D_, B_,
          nullptr, 0, 0,
          scale, src_pad, S_, nullptr, 0, 0, 0, 0, 0);
      softmax1024b<0><<<dim3((unsigned)(G * B_ * T_)), blk, 0, stream>>>(logit);
      gemm_bt<bf16_t, 0, 2><<<dim3(D_ / 128, T_ / 64, G * B_), blk, 0, stream>>>(
          logit, BTS, (int64_t)T_ * S_, S_,
          mvT, 0, (int64_t)D_ * S_, S_,
          hoAll + (int64_t)h0 * D_, D_, (int64_t)T_ * H_ * D_, H_ * D_,
          S_, B_,
          nullptr, 0, 0, 1.f, nullptr, 0, nullptr, 0, 0, 0, 0, 0);
    }
    gemm_bt<float, 0, 2><<<dim3(D_ / 128, M8 / 64, 1), blk, 0, stream>>>(
        hoAll, 0, 0, H_ * D_, WomT, 0, 0, H_ * D_, outf, 0, 0, D_,
        H_ * D_, 1, bom, 0, 0, 1.f, nullptr, 0, nullptr, 0, 0, 0, 0, 0);
    add_ln512<<<dim3(M8), dim3(128), 0, stream>>>(outf, x1f, g2, be2, x1f, actb);
  } else {
    // =========== Path B: per-head (proven fallback) ===========
    bf16_t* qkvH  = (bf16_t*)alloc(3 * BTD * 2);
    bf16_t* vtH   = (bf16_t*)alloc(BTD * 2);
    bf16_t* logit = (bf16_t*)alloc(BTS * 2);
    bf16_t* hoH   = (bf16_t*)alloc(BTD * 2);
    ffh = qkvH;

    for (int h = 0; h < H_; ++h) {
      gemm_bt<bf16_t, 0, 2><<<dim3(D_ / 128, M8 / 64, 3), blk, 0, stream>>>(
          actb, 0, 0, D_,
          WTqkv + (int64_t)h * DD, (int64_t)H_ * DD, 0, D_,
          qkvH, BTD, 0, D_,
          D_, 1,
          bqkv + h * D_, (int64_t)H_ * D_, 0,
          1.f, nullptr, 0, nullptr, 0, 0, 0, 0, 0);
      tcast<bf16_t><<<dim3(D_ / 32, T_ / 32, B_), blk, 0, stream>>>(
          qkvH + 2 * BTD, vtH, T_, D_);
      gemm_bt<bf16_t, 2, 2><<<dim3(S_ / 128, T_ / 64, B_), blk, 0, stream>>>(
          qkvH, 0, (int64_t)T_ * D_, D_,
          qkvH + BTD, 0, (int64_t)T_ * D_, D_,
          logit, 0, (int64_t)T_ * S_, S_,
          D_, B_,
          nullptr, 0, 0,
          scale, tgt_pad, T_, tgt_sub, S_, /*causal=*/2, 0, 0, 0);
      softmax1024b<1><<<dim3((unsigned)(B_ * T_)), blk, 0, stream>>>(logit);
      gemm_bt<bf16_t, 0, 2><<<dim3(D_ / 128, T_ / 64, B_), blk, 0, stream>>>(
          logit, 0, (int64_t)T_ * S_, S_,
          vtH, 0, (int64_t)D_ * T_, T_,
          hoH, 0, (int64_t)T_ * D_, D_,
          S_, B_,
          nullptr, 0, 0, 1.f, nullptr, 0, nullptr, 0, 0, 0, /*kcap=*/1, 0);
      gemm_bt<float, 3, 2><<<dim3(D_ / 128, M8 / 64, 1), blk, 0, stream>>>(
          hoH, 0, 0, D_,
          WoT + (int64_t)h * D_, 0, 0, H_ * D_,
          outf, 0, 0, D_,
          D_, 1,
          bo, 0, 0, 1.f, nullptr, 0, nullptr, 0, 0, (h == 0) ? 1 : 0, 0, 0);
    }
    add_ln512<<<dim3(M8), dim3(128), 0, stream>>>(outf, x, g1, be1, x1f, actb);

    for (int h = 0; h < H_; ++h) {
      gemm_bt<bf16_t, 0, 2><<<dim3(D_ / 128, M8 / 64, 1), blk, 0, stream>>>(
          actb, 0, 0, D_,
          WqmT + (int64_t)h * DD, 0, 0, D_,
          qkvH, 0, 0, D_,
          D_, 1,
          bqm + h * D_, 0, 0,
          1.f, nullptr, 0, nullptr, 0, 0, 0, 0, 0);
      gemm_bt<bf16_t, 2, 2><<<dim3(S_ / 128, T_ / 64, B_), blk, 0, stream>>>(
          qkvH, 0, (int64_t)T_ * D_, D_,
          mkb, 0, (int64_t)S_ * D_, D_,
          logit, 0, (int64_t)T_ * S_, S_,
          D_, B_,
          nullptr, 0, 0,
          scale, src_pad, S_, nullptr, 0, 0, 0, 0, 0);
      softmax1024b<0><<<dim3((unsigned)(B_ * T_)), blk, 0, stream>>>(logit);
      gemm_bt<bf16_t, 0, 2><<<dim3(D_ / 128, T_ / 64, B_), blk, 0, stream>>>(
          logit, 0, (int64_t)T_ * S_, S_,
          mvT, 0, (int64_t)D_ * S_, S_,
          hoH, 0, (int64_t)T_ * D_, D_,
          S_, B_,
          nullptr, 0, 0, 1.f, nullptr, 0, nullptr, 0, 0, 0, 0, 0);
      gemm_bt<float, 3, 2><<<dim3(D_ / 128, M8 / 64, 1), blk, 0, stream>>>(
          hoH, 0, 0, D_,
          WomT + (int64_t)h * D_, 0, 0, H_ * D_,
          outf, 0, 0, D_,
          D_, 1,
          bom, 0, 0, 1.f, nullptr, 0, nullptr, 0, 0, (h == 0) ? 1 : 0, 0, 0);
    }
    add_ln512<<<dim3(M8), dim3(128), 0, stream>>>(outf, x1f, g2, be2, x1f, actb);
  }

  // ---- FFN (common)
  gemm_bt<bf16_t, 1, 2><<<dim3(F_ / 128, M8 / 64, 1), blk, 0, stream>>>(
      actb, 0, 0, D_, W1T, 0, 0, D_, ffh, 0, 0, F_,
      D_, 1, b1, 0, 0, 1.f, nullptr, 0, nullptr, 0, 0, 0, 0, 0);
  gemm_bt<float, 0, 2><<<dim3(D_ / 128, M8 / 64, 1), blk, 0, stream>>>(
      ffh, 0, 0, F_, W2T, 0, 0, F_, outf, 0, 0, D_,
      F_, 1, b2, 0, 0, 1.f, nullptr, 0, nullptr, 0, 0, 0, 0, 0);
  add_ln512<<<dim3(M8), dim3(128), 0, stream>>>(outf, x1f, g3, be3, outf, nullptr);

  (void)in_sizes; (void)n_in; (void)out_size;
}

// Round 15
// 1094.905 us; speedup vs baseline: 1.1139x; 1.1139x over previous
//
#include <hip/hip_runtime.h>
#include <hip/hip_bf16.h>
#include <cstdint>

#define DEV __device__ __forceinline__

typedef __bf16 bf16_t;
typedef bf16_t bf16x8 __attribute__((ext_vector_type(8)));
typedef float  f32x4  __attribute__((ext_vector_type(4)));

static constexpr int B_ = 8, T_ = 1024, S_ = 1024, D_ = 512, H_ = 8, F_ = 2048;

typedef const __attribute__((address_space(1))) void* gas_ptr;
typedef __attribute__((address_space(3))) void* las_ptr;

DEV void gload_lds16(const void* g, void* l) {
  __builtin_amdgcn_global_load_lds((gas_ptr)g, (las_ptr)l, 16, 0, 0);
}

// ---------------------------------------------------------------------------
// bf16 GEMM:  C[z] = A[z] (M x K, row-major) * BT[z]^T  (BT is N x K row-major)
// Proven R10 config: BM = MI*32 (MI=2 -> 64), BN = 128. 48 KB LDS double
// buffer, 3 blocks/CU. Counted-vmcnt (steady vmcnt(6)) + raw barriers +
// T2 XOR-swizzle (pre-swizzled global source + swizzled ds_read) +
// T5 setprio + T1 bijective XCD swizzle.
// EPI 0:+bias | 1:+bias,relu | 2:*scale+pad+subsq | 3: accumulate fp32
// causal: 0=none, 2=fully-masked blocks write NOTHING (softmax zero-fill)
// kcap: causal K-limit (rows m0.. need K < m0+BM only)
// ---------------------------------------------------------------------------
template<typename OutT, int EPI, int MI>
__global__ __launch_bounds__(256, (MI == 2) ? 3 : 2) void gemm_bt(
    const bf16_t* __restrict__ A,  int64_t aH, int64_t aB, int lda,
    const bf16_t* __restrict__ BT, int64_t bH, int64_t bB, int ldb,
    OutT* __restrict__ C,          int64_t cH, int64_t cB, int ldo,
    int K, int ZB,
    const float* __restrict__ bias, int64_t biasH, int64_t biasB,
    float scale,
    const float* __restrict__ pad, int64_t padB,
    const float* __restrict__ subsq, int subsq_ld, int causal,
    int initC, int kcap)
{
  constexpr int BM = MI * 32;          // 64 or 128

  // ---- bijective XCD-chunked swizzle over the flattened grid (m204)
  const unsigned gx = gridDim.x, gy = gridDim.y;
  const unsigned nwg = gx * gy * gridDim.z;
  const unsigned orig = (blockIdx.z * gy + blockIdx.y) * gx + blockIdx.x;
  const unsigned q8 = nwg >> 3, r8 = nwg & 7;
  const unsigned xcd = orig & 7, cidx = orig >> 3;
  const unsigned swz = (xcd < r8 ? xcd * (q8 + 1)
                                 : r8 * (q8 + 1) + (xcd - r8) * q8) + cidx;
  const unsigned bz = swz / (gx * gy);
  const unsigned rm = swz - bz * gx * gy;
  const unsigned by = rm / gx;
  const unsigned bx = rm - by * gx;

  const int z  = bz;
  const int zh = z / ZB, zb = z - zh * ZB;
  A  += zh * aH + zb * aB;
  BT += zh * bH + zb * bB;
  C  += zh * cH + zb * cB;
  const int m0 = by * BM;
  const int n0 = bx << 7;

  // fully-masked causal block
  const bool skip = (EPI == 2) && causal && (n0 >= m0 + BM);
  if (skip && causal == 2) return;     // write nothing; nobody reads it

  __shared__ __align__(16) bf16_t As[2][BM * 64];
  __shared__ __align__(16) bf16_t Bs[2][128 * 64];

  const int tid  = threadIdx.x;
  const int lane = tid & 63;
  const int wr   = tid >> 7;          // wave row (0..1)
  const int wc   = (tid >> 6) & 1;    // wave col (0..1)

  f32x4 acc[MI][4] = {};

  int Klim = K;
  if (kcap) { const int lim = m0 + BM; Klim = lim < K ? lim : K; }

  // stage with pre-swizzled global column: LDS slot (row, s) <- global granule
  // (row, s ^ (row&7)); reader XORs the same way -> conflict-free ds_read_b128
  auto stage = [&](int buf, int kb) {
    #pragma unroll
    for (int i = 0; i < MI; ++i) {     // A: BM*64 elems = MI chunks/thread
      const int c = i * 256 + tid;
      const int row = c >> 3;
      const int col = (((c & 7) ^ (row & 7)) << 3);
      gload_lds16(A + (int64_t)(m0 + row) * lda + kb + col, &As[buf][c * 8]);
    }
    #pragma unroll
    for (int i = 0; i < 4; ++i) {      // B: 128*64 elems = 4 chunks/thread
      const int c = i * 256 + tid;
      const int row = c >> 3;
      const int col = (((c & 7) ^ (row & 7)) << 3);
      gload_lds16(BT + (int64_t)(n0 + row) * ldb + kb + col, &Bs[buf][c * 8]);
    }
  };

  if (!skip) {
    const int NT = Klim >> 6;
    stage(0, 0);
    if (NT > 1) stage(1, 64);
    const int hi = lane >> 4, r7 = lane & 7;
    for (int t = 0; t < NT; ++t) {
      // wait tile t complete; tile t+1 (MI+4 loads/thread) stays in flight
      if (t + 1 < NT) {
        if constexpr (MI == 2) asm volatile("s_waitcnt vmcnt(6)" ::: "memory");
        else                   asm volatile("s_waitcnt vmcnt(8)" ::: "memory");
      } else {
        asm volatile("s_waitcnt vmcnt(0)" ::: "memory");
      }
      __builtin_amdgcn_s_barrier();              // raw: no implicit drain
      __builtin_amdgcn_sched_barrier(0);
      const int cur = t & 1;
      // pre-read ALL fragments of tile t (buffer gets overwritten below)
      bf16x8 af[MI][2], bq[4][2];
      #pragma unroll
      for (int ks = 0; ks < 2; ++ks) {
        #pragma unroll
        for (int i = 0; i < MI; ++i)
          af[i][ks] = *(const bf16x8*)&As[cur][(wr * (MI * 16) + i * 16 + (lane & 15)) * 64 + (((ks * 4 + hi) ^ r7) << 3)];
        #pragma unroll
        for (int i = 0; i < 4; ++i)
          bq[i][ks] = *(const bf16x8*)&Bs[cur][(wc * 64 + i * 16 + (lane & 15)) * 64 + (((ks * 4 + hi) ^ r7) << 3)];
      }
      asm volatile("s_waitcnt lgkmcnt(0)" ::: "memory");
      __builtin_amdgcn_sched_barrier(0);
      __builtin_amdgcn_s_barrier();              // all waves done reading buf
      if (t + 2 < NT) stage(cur, (t + 2) << 6);  // restage freed buffer early
      __builtin_amdgcn_sched_barrier(0);         // keep MFMAs after stage issue
      __builtin_amdgcn_s_setprio(1);
      #pragma unroll
      for (int ks = 0; ks < 2; ++ks)
        #pragma unroll
        for (int mi = 0; mi < MI; ++mi)
          #pragma unroll
          for (int ni = 0; ni < 4; ++ni)
            acc[mi][ni] = __builtin_amdgcn_mfma_f32_16x16x32_bf16(af[mi][ks], bq[ni][ks], acc[mi][ni], 0, 0, 0);
      __builtin_amdgcn_s_setprio(0);
    }
  }

  // epilogue; C/D frag layout: col = lane&15, row = 4*(lane>>4)+r
  const float* bz_ = (EPI != 2 && bias) ? bias + zh * biasH + zb * biasB : nullptr;
  const float* pz  = (EPI == 2 && pad)  ? pad + zb * padB : nullptr;
  #pragma unroll
  for (int ni = 0; ni < 4; ++ni) {
    const int col = n0 + wc * 64 + ni * 16 + (lane & 15);
    const float badd = bz_ ? bz_[col] : 0.f;
    const float pv   = pz ? pz[col] : 0.f;
    #pragma unroll
    for (int mi = 0; mi < MI; ++mi) {
      const int rowb = m0 + wr * (MI * 16) + mi * 16 + ((lane >> 4) << 2);
      #pragma unroll
      for (int r = 0; r < 4; ++r) {
        const int row = rowb + r;
        const int64_t idx = (int64_t)row * ldo + col;
        float v = acc[mi][ni][r];
        if (EPI == 2) {
          v = v * scale + pv;
          if (subsq) v += subsq[(int64_t)row * subsq_ld + col];
        } else if (EPI == 3) {
          v += initC ? badd : (float)C[idx];
        } else {
          v += badd;
          if (EPI == 1) v = fmaxf(v, 0.f);
        }
        if constexpr (sizeof(OutT) == 2) C[idx] = (OutT)v;
        else                             C[idx] = v;
      }
    }
  }
}

// ---------------------------------------------------------------------------
// In-place row softmax over 1024 bf16 logits. One block (256 thr) per row.
// CAUSAL=1: row length = (blockIdx % T)+1; reads only the causal prefix,
// zero-fills up to the next multiple of 64 (what PV's kcap reads).
// ---------------------------------------------------------------------------
template<int CAUSAL>
__global__ __launch_bounds__(256) void softmax1024b(bf16_t* __restrict__ P)
{
  const int64_t row = blockIdx.x;
  const int len = CAUSAL ? (int)(row % T_) + 1 : 1024;
  const int tid = threadIdx.x;
  const int j4 = tid << 2;
  float v0 = -3e38f, v1 = -3e38f, v2 = -3e38f, v3 = -3e38f;
  if (j4 < len) {
    union { bf16_t b[4]; uint2 u; } in;
    in.u = ((const uint2*)(P + row * 1024))[tid];
    v0 = (float)in.b[0];
    if (j4 + 1 < len) v1 = (float)in.b[1];
    if (j4 + 2 < len) v2 = (float)in.b[2];
    if (j4 + 3 < len) v3 = (float)in.b[3];
  }
  float m = fmaxf(fmaxf(v0, v1), fmaxf(v2, v3));
  #pragma unroll
  for (int off = 32; off; off >>= 1) m = fmaxf(m, __shfl_xor(m, off));
  __shared__ float red[8];
  if ((tid & 63) == 0) red[tid >> 6] = m;
  __syncthreads();
  m = fmaxf(fmaxf(red[0], red[1]), fmaxf(red[2], red[3]));
  const float e0 = (j4     < len) ? __expf(v0 - m) : 0.f;
  const float e1 = (j4 + 1 < len) ? __expf(v1 - m) : 0.f;
  const float e2 = (j4 + 2 < len) ? __expf(v2 - m) : 0.f;
  const float e3 = (j4 + 3 < len) ? __expf(v3 - m) : 0.f;
  float s = e0 + e1 + e2 + e3;
  #pragma unroll
  for (int off = 32; off; off >>= 1) s += __shfl_xor(s, off);
  if ((tid & 63) == 0) red[4 + (tid >> 6)] = s;
  __syncthreads();
  const float inv = 1.f / (red[4] + red[5] + red[6] + red[7]);
  const int lenc = CAUSAL ? ((len + 63) & ~63) : 1024;  // PV reads < ceil64(len)
  if (j4 < lenc) {
    union { bf16_t b[4]; uint2 u; } o;
    o.b[0] = (bf16_t)(e0 * inv); o.b[1] = (bf16_t)(e1 * inv);
    o.b[2] = (bf16_t)(e2 * inv); o.b[3] = (bf16_t)(e3 * inv);
    ((uint2*)(P + row * 1024))[tid] = o.u;
  }
}

// ---------------------------------------------------------------------------
// y = LayerNorm(a + r) * g + b ; yf fp32 (may alias a or r: element-local),
// yb bf16 (nullable). D=512, block 128.
// ---------------------------------------------------------------------------
__global__ __launch_bounds__(128) void add_ln512(
    const float* __restrict__ a, const float* __restrict__ r,
    const float* __restrict__ g, const float* __restrict__ be,
    float* __restrict__ yf, bf16_t* __restrict__ yb)
{
  const int64_t row = blockIdx.x;
  const int tid = threadIdx.x;
  const float4 va = ((const float4*)(a + row * 512))[tid];
  const float4 vr = ((const float4*)(r + row * 512))[tid];
  const float x0 = va.x + vr.x, x1 = va.y + vr.y, x2 = va.z + vr.z, x3 = va.w + vr.w;
  float s = x0 + x1 + x2 + x3;
  float q = x0 * x0 + x1 * x1 + x2 * x2 + x3 * x3;
  #pragma unroll
  for (int off = 32; off; off >>= 1) { s += __shfl_xor(s, off); q += __shfl_xor(q, off); }
  __shared__ float red[4];
  if ((tid & 63) == 0) { red[tid >> 6] = s; red[2 + (tid >> 6)] = q; }
  __syncthreads();
  s = red[0] + red[1]; q = red[2] + red[3];
  const float mean = s * (1.f / 512.f);
  const float var  = q * (1.f / 512.f) - mean * mean;
  const float rstd = rsqrtf(var + 1e-5f);
  const float4 g4 = ((const float4*)g)[tid];
  const float4 b4 = ((const float4*)be)[tid];
  const float y0 = (x0 - mean) * rstd * g4.x + b4.x;
  const float y1 = (x1 - mean) * rstd * g4.y + b4.y;
  const float y2 = (x2 - mean) * rstd * g4.z + b4.z;
  const float y3 = (x3 - mean) * rstd * g4.w + b4.w;
  float4 o; o.x = y0; o.y = y1; o.z = y2; o.w = y3;
  ((float4*)(yf + row * 512))[tid] = o;
  if (yb) {
    union { bf16_t b[4]; uint2 u; } ob;
    ob.b[0] = (bf16_t)y0; ob.b[1] = (bf16_t)y1; ob.b[2] = (bf16_t)y2; ob.b[3] = (bf16_t)y3;
    ((uint2*)(yb + row * 512))[tid] = ob.u;
  }
}

// ---------------------------------------------------------------------------
// Transpose + cast: src [z][R][C] (InT) -> dst [z][C][R] (bf16)
// ---------------------------------------------------------------------------
template<typename InT>
__global__ __launch_bounds__(256) void tcast(
    const InT* __restrict__ src, bf16_t* __restrict__ dst, int R, int C)
{
  __shared__ float t[32][33];
  const int64_t zo = (int64_t)blockIdx.z * R * C;
  const int c0 = blockIdx.x << 5, r0 = blockIdx.y << 5;
  const int tx = threadIdx.x & 31, ty = threadIdx.x >> 5;
  #pragma unroll
  for (int i = 0; i < 32; i += 8)
    t[ty + i][tx] = (float)src[zo + (int64_t)(r0 + ty + i) * C + c0 + tx];
  __syncthreads();
  #pragma unroll
  for (int i = 0; i < 32; i += 8)
    dst[zo + (int64_t)(c0 + ty + i) * R + r0 + tx] = (bf16_t)t[tx][ty + i];
}

__global__ __launch_bounds__(256) void castf2b(
    const float* __restrict__ s, bf16_t* __restrict__ d, int n4)
{
  const int i = blockIdx.x * 256 + threadIdx.x;
  if (i >= n4) return;
  const float4 v = ((const float4*)s)[i];
  union { bf16_t b[4]; uint2 u; } o;
  o.b[0] = (bf16_t)v.x; o.b[1] = (bf16_t)v.y; o.b[2] = (bf16_t)v.z; o.b[3] = (bf16_t)v.w;
  ((uint2*)d)[i] = o.u;
}

__global__ __launch_bounds__(256) void pack3(
    const float* __restrict__ a, const float* __restrict__ b,
    const float* __restrict__ c, float* __restrict__ d, int n)
{
  const int i = blockIdx.x * 256 + threadIdx.x;
  if (i < n) { d[i] = a[i]; d[n + i] = b[i]; d[2 * n + i] = c[i]; }
}

// ---------------------------------------------------------------------------
extern "C" void kernel_launch(void* const* d_in, const int* in_sizes, int n_in,
                              void* d_out, int out_size, void* d_ws, size_t ws_size,
                              hipStream_t stream)
{
  const float* x       = (const float*)d_in[0];
  const float* src_pad = (const float*)d_in[1];
  const float* tgt_pad = (const float*)d_in[3];
  const float* tgt_sub = (const float*)d_in[4];
  const float* mk      = (const float*)d_in[5];
  const float* mv      = (const float*)d_in[6];
  const float* Wq  = (const float*)d_in[7];
  const float* bq  = (const float*)d_in[8];
  const float* Wk  = (const float*)d_in[9];
  const float* bk  = (const float*)d_in[10];
  const float* Wv  = (const float*)d_in[11];
  const float* bv  = (const float*)d_in[12];
  const float* Wo  = (const float*)d_in[13];
  const float* bo  = (const float*)d_in[14];
  const float* Wqm = (const float*)d_in[15];
  const float* bqm = (const float*)d_in[16];
  const float* Wom = (const float*)d_in[17];
  const float* bom = (const float*)d_in[18];
  const float* W1  = (const float*)d_in[19];
  const float* b1  = (const float*)d_in[20];
  const float* W2  = (const float*)d_in[21];
  const float* b2  = (const float*)d_in[22];
  const float* g1  = (const float*)d_in[23];
  const float* be1 = (const float*)d_in[24];
  const float* g2  = (const float*)d_in[25];
  const float* be2 = (const float*)d_in[26];
  const float* g3  = (const float*)d_in[27];
  const float* be3 = (const float*)d_in[28];
  float* outf = (float*)d_out;   // fp32 projection target / final out

  constexpr int64_t BTD = (int64_t)B_ * T_ * D_;  // 4 Mi elements
  constexpr int64_t BTS = (int64_t)B_ * T_ * S_;  // 8 Mi elements
  constexpr int64_t DD  = (int64_t)D_ * D_;
  const int M8 = B_ * T_;                          // 8192

  char* p = (char*)d_ws;
  auto alloc = [&](int64_t bytes) -> void* {
    char* r = p; p += (bytes + 255) & ~(int64_t)255; return (void*)r;
  };
  // ---- persistent (~68 MiB)
  bf16_t* WTqkv = (bf16_t*)alloc(3 * H_ * DD * 2);            // [3][H][D][D]
  bf16_t* WoT   = (bf16_t*)alloc((int64_t)D_ * H_ * D_ * 2);  // [512][4096]
  bf16_t* WqmT  = (bf16_t*)alloc(H_ * DD * 2);                // [H][D][D]
  bf16_t* WomT  = (bf16_t*)alloc((int64_t)D_ * H_ * D_ * 2);  // [512][4096]
  bf16_t* W1T   = (bf16_t*)alloc((int64_t)F_ * D_ * 2);       // [2048][512]
  bf16_t* W2T   = (bf16_t*)alloc((int64_t)D_ * F_ * 2);       // [512][2048]
  float*  bqkv  = (float*)alloc(3 * H_ * D_ * 4);
  bf16_t* actb  = (bf16_t*)alloc(BTD * 2);                    // xb -> x1b -> x2b
  bf16_t* mkb   = (bf16_t*)alloc(BTD * 2);
  bf16_t* mvT   = (bf16_t*)alloc(BTD * 2);                    // [B][D][S]
  float*  x1f   = (float*)alloc(BTD * 4);                     // x1 -> x2 (in-place)

  const int64_t remain = (int64_t)ws_size - (int64_t)(p - (char*)d_ws);
  const int64_t perG   = 3 * BTD * 2 + BTD * 2 + BTS * 2;     // qkv+vt+logit per head
  const int64_t hoCat  = (int64_t)B_ * T_ * H_ * D_ * 2;      // cat layout [B][T][H*D]
  int G = 0;
  for (int g = 8; g >= 1; g >>= 1)
    if (remain >= hoCat + (int64_t)g * perG + (4 << 20)) { G = g; break; }
  const int64_t needB = 3 * BTD * 2 + BTD * 2 + BTS * 2 + BTD * 2 + (1 << 20);
  if (G == 0 && remain < needB) return;  // clean failure: ws too small

  const float scale = 1.0f / sqrtf((float)D_);
  dim3 blk(256);

  // ---- prologue: casts / transposes (persistent buffers only)
  castf2b<<<dim3((unsigned)(BTD / 4 / 256)), blk, 0, stream>>>(x, actb, (int)(BTD / 4));
  castf2b<<<dim3((unsigned)(BTD / 4 / 256)), blk, 0, stream>>>(mk, mkb, (int)(BTD / 4));
  tcast<float><<<dim3(D_ / 32, S_ / 32, B_), blk, 0, stream>>>(mv, mvT, S_, D_);
  tcast<float><<<dim3(D_ / 32, D_ / 32, H_), blk, 0, stream>>>(Wq, WTqkv, D_, D_);
  tcast<float><<<dim3(D_ / 32, D_ / 32, H_), blk, 0, stream>>>(Wk, WTqkv + H_ * DD, D_, D_);
  tcast<float><<<dim3(D_ / 32, D_ / 32, H_), blk, 0, stream>>>(Wv, WTqkv + 2 * H_ * DD, D_, D_);
  tcast<float><<<dim3(D_ / 32, (H_ * D_) / 32, 1), blk, 0, stream>>>(Wo, WoT, H_ * D_, D_);
  tcast<float><<<dim3(D_ / 32, D_ / 32, H_), blk, 0, stream>>>(Wqm, WqmT, D_, D_);
  tcast<float><<<dim3(D_ / 32, (H_ * D_) / 32, 1), blk, 0, stream>>>(Wom, WomT, H_ * D_, D_);
  tcast<float><<<dim3(F_ / 32, D_ / 32, 1), blk, 0, stream>>>(W1, W1T, D_, F_);
  tcast<float><<<dim3(D_ / 32, F_ / 32, 1), blk, 0, stream>>>(W2, W2T, F_, D_);
  pack3<<<dim3((H_ * D_ + 255) / 256), blk, 0, stream>>>(bq, bk, bv, bqkv, H_ * D_);

  bf16_t* ffh = nullptr;  // [8192][2048] alias set per path

  if (G > 0) {
    // =========== Path A: head-group batching, cat-layout ho ===========
    bf16_t* hoAll = (bf16_t*)alloc(hoCat);                    // [B][T][H*D]
    bf16_t* qkv   = (bf16_t*)alloc(3 * G * BTD * 2);          // [3][G][B][T][D]
    bf16_t* vt    = (bf16_t*)alloc((int64_t)G * BTD * 2);     // [G*B][D][T]
    bf16_t* logit = (bf16_t*)alloc((int64_t)G * BTS * 2);     // [G][B][T][S]
    ffh = qkv;

    // ---- self-attention
    for (int h0 = 0; h0 < H_; h0 += G) {
      gemm_bt<bf16_t, 0, 2><<<dim3(D_ / 128, M8 / 64, 3 * G), blk, 0, stream>>>(
          actb, 0, 0, D_,
          WTqkv + (int64_t)h0 * DD, (int64_t)H_ * DD, DD, D_,
          qkv, (int64_t)G * BTD, BTD, D_,
          D_, G,
          bqkv + h0 * D_, (int64_t)H_ * D_, D_,
          1.f, nullptr, 0, nullptr, 0, 0, 0, 0);
      tcast<bf16_t><<<dim3(D_ / 32, T_ / 32, G * B_), blk, 0, stream>>>(
          qkv + (int64_t)2 * G * BTD, vt, T_, D_);
      gemm_bt<bf16_t, 2, 2><<<dim3(S_ / 128, T_ / 64, G * B_), blk, 0, stream>>>(
          qkv, BTD, (int64_t)T_ * D_, D_,
          qkv + (int64_t)G * BTD, BTD, (int64_t)T_ * D_, D_,
          logit, BTS, (int64_t)T_ * S_, S_,
          D_, B_,
          nullptr, 0, 0,
          scale, tgt_pad, T_, tgt_sub, S_, /*causal=*/2, 0, 0);
      softmax1024b<1><<<dim3((unsigned)(G * B_ * T_)), blk, 0, stream>>>(logit);
      gemm_bt<bf16_t, 0, 2><<<dim3(D_ / 128, T_ / 64, G * B_), blk, 0, stream>>>(
          logit, BTS, (int64_t)T_ * S_, S_,
          vt, (int64_t)B_ * D_ * T_, (int64_t)D_ * T_, T_,
          hoAll + (int64_t)h0 * D_, D_, (int64_t)T_ * H_ * D_, H_ * D_,
          S_, B_,
          nullptr, 0, 0, 1.f, nullptr, 0, nullptr, 0, 0, 0, /*kcap=*/1);
    }
    gemm_bt<float, 0, 2><<<dim3(D_ / 128, M8 / 64, 1), blk, 0, stream>>>(
        hoAll, 0, 0, H_ * D_, WoT, 0, 0, H_ * D_, outf, 0, 0, D_,
        H_ * D_, 1, bo, 0, 0, 1.f, nullptr, 0, nullptr, 0, 0, 0, 0);
    add_ln512<<<dim3(M8), dim3(128), 0, stream>>>(outf, x, g1, be1, x1f, actb);

    // ---- cross-attention
    for (int h0 = 0; h0 < H_; h0 += G) {
      gemm_bt<bf16_t, 0, 2><<<dim3(D_ / 128, M8 / 64, G), blk, 0, stream>>>(
          actb, 0, 0, D_,
          WqmT + (int64_t)h0 * DD, 0, DD, D_,
          qkv, 0, BTD, D_,
          D_, G,
          bqm + h0 * D_, 0, D_,
          1.f, nullptr, 0, nullptr, 0, 0, 0, 0);
      gemm_bt<bf16_t, 2, 2><<<dim3(S_ / 128, T_ / 64, G * B_), blk, 0, stream>>>(
          qkv, BTD, (int64_t)T_ * D_, D_,
          mkb, 0, (int64_t)S_ * D_, D_,
          logit, BTS, (int64_t)T_ * S_, S_,
          D_, B_,
          nullptr, 0, 0,
          scale, src_pad, S_, nullptr, 0, 0, 0, 0);
      softmax1024b<0><<<dim3((unsigned)(G * B_ * T_)), blk, 0, stream>>>(logit);
      gemm_bt<bf16_t, 0, 2><<<dim3(D_ / 128, T_ / 64, G * B_), blk, 0, stream>>>(
          logit, BTS, (int64_t)T_ * S_, S_,
          mvT, 0, (int64_t)D_ * S_, S_,
          hoAll + (int64_t)h0 * D_, D_, (int64_t)T_ * H_ * D_, H_ * D_,
          S_, B_,
          nullptr, 0, 0, 1.f, nullptr, 0, nullptr, 0, 0, 0, 0);
    }
    gemm_bt<float, 0, 2><<<dim3(D_ / 128, M8 / 64, 1), blk, 0, stream>>>(
        hoAll, 0, 0, H_ * D_, WomT, 0, 0, H_ * D_, outf, 0, 0, D_,
        H_ * D_, 1, bom, 0, 0, 1.f, nullptr, 0, nullptr, 0, 0, 0, 0);
    add_ln512<<<dim3(M8), dim3(128), 0, stream>>>(outf, x1f, g2, be2, x1f, actb);
  } else {
    // =========== Path B: per-head with accumulate out-proj ===========
    bf16_t* qkvH  = (bf16_t*)alloc(3 * BTD * 2);
    bf16_t* vtH   = (bf16_t*)alloc(BTD * 2);
    bf16_t* logit = (bf16_t*)alloc(BTS * 2);
    bf16_t* hoH   = (bf16_t*)alloc(BTD * 2);
    ffh = qkvH;

    for (int h = 0; h < H_; ++h) {
      gemm_bt<bf16_t, 0, 2><<<dim3(D_ / 128, M8 / 64, 3), blk, 0, stream>>>(
          actb, 0, 0, D_,
          WTqkv + (int64_t)h * DD, (int64_t)H_ * DD, 0, D_,
          qkvH, BTD, 0, D_,
          D_, 1,
          bqkv + h * D_, (int64_t)H_ * D_, 0,
          1.f, nullptr, 0, nullptr, 0, 0, 0, 0);
      tcast<bf16_t><<<dim3(D_ / 32, T_ / 32, B_), blk, 0, stream>>>(
          qkvH + 2 * BTD, vtH, T_, D_);
      gemm_bt<bf16_t, 2, 2><<<dim3(S_ / 128, T_ / 64, B_), blk, 0, stream>>>(
          qkvH, 0, (int64_t)T_ * D_, D_,
          qkvH + BTD, 0, (int64_t)T_ * D_, D_,
          logit, 0, (int64_t)T_ * S_, S_,
          D_, B_,
          nullptr, 0, 0,
          scale, tgt_pad, T_, tgt_sub, S_, 2, 0, 0);
      softmax1024b<1><<<dim3((unsigned)(B_ * T_)), blk, 0, stream>>>(logit);
      gemm_bt<bf16_t, 0, 2><<<dim3(D_ / 128, T_ / 64, B_), blk, 0, stream>>>(
          logit, 0, (int64_t)T_ * S_, S_,
          vtH, 0, (int64_t)D_ * T_, T_,
          hoH, 0, (int64_t)T_ * D_, D_,
          S_, B_,
          nullptr, 0, 0, 1.f, nullptr, 0, nullptr, 0, 0, 0, /*kcap=*/1);
      gemm_bt<float, 3, 2><<<dim3(D_ / 128, M8 / 64, 1), blk, 0, stream>>>(
          hoH, 0, 0, D_,
          WoT + (int64_t)h * D_, 0, 0, H_ * D_,
          outf, 0, 0, D_,
          D_, 1,
          bo, 0, 0, 1.f, nullptr, 0, nullptr, 0, 0, (h == 0) ? 1 : 0, 0);
    }
    add_ln512<<<dim3(M8), dim3(128), 0, stream>>>(outf, x, g1, be1, x1f, actb);

    for (int h = 0; h < H_; ++h) {
      gemm_bt<bf16_t, 0, 2><<<dim3(D_ / 128, M8 / 64, 1), blk, 0, stream>>>(
          actb, 0, 0, D_,
          WqmT + (int64_t)h * DD, 0, 0, D_,
          qkvH, 0, 0, D_,
          D_, 1,
          bqm + h * D_, 0, 0,
          1.f, nullptr, 0, nullptr, 0, 0, 0, 0);
      gemm_bt<bf16_t, 2, 2><<<dim3(S_ / 128, T_ / 64, B_), blk, 0, stream>>>(
          qkvH, 0, (int64_t)T_ * D_, D_,
          mkb, 0, (int64_t)S_ * D_, D_,
          logit, 0, (int64_t)T_ * S_, S_,
          D_, B_,
          nullptr, 0, 0,
          scale, src_pad, S_, nullptr, 0, 0, 0, 0);
      softmax1024b<0><<<dim3((unsigned)(B_ * T_)), blk, 0, stream>>>(logit);
      gemm_bt<bf16_t, 0, 2><<<dim3(D_ / 128, T_ / 64, B_), blk, 0, stream>>>(
          logit, 0, (int64_t)T_ * S_, S_,
          mvT, 0, (int64_t)D_ * S_, S_,
          hoH, 0, (int64_t)T_ * D_, D_,
          S_, B_,
          nullptr, 0, 0, 1.f, nullptr, 0, nullptr, 0, 0, 0, 0);
      gemm_bt<float, 3, 2><<<dim3(D_ / 128, M8 / 64, 1), blk, 0, stream>>>(
          hoH, 0, 0, D_,
          WomT + (int64_t)h * D_, 0, 0, H_ * D_,
          outf, 0, 0, D_,
          D_, 1,
          bom, 0, 0, 1.f, nullptr, 0, nullptr, 0, 0, (h == 0) ? 1 : 0, 0);
    }
    add_ln512<<<dim3(M8), dim3(128), 0, stream>>>(outf, x1f, g2, be2, x1f, actb);
  }

  // ---- FFN (common)
  gemm_bt<bf16_t, 1, 2><<<dim3(F_ / 128, M8 / 64, 1), blk, 0, stream>>>(
      actb, 0, 0, D_, W1T, 0, 0, D_, ffh, 0, 0, F_,
      D_, 1, b1, 0, 0, 1.f, nullptr, 0, nullptr, 0, 0, 0, 0);
  gemm_bt<float, 0, 2><<<dim3(D_ / 128, M8 / 64, 1), blk, 0, stream>>>(
      ffh, 0, 0, F_, W2T, 0, 0, F_, outf, 0, 0, D_,
      F_, 1, b2, 0, 0, 1.f, nullptr, 0, nullptr, 0, 0, 0, 0);
  add_ln512<<<dim3(M8), dim3(128), 0, stream>>>(outf, x1f, g3, be3, outf, nullptr);

  (void)in_sizes; (void)n_in; (void)out_size;
}

// Round 16
// 1086.981 us; speedup vs baseline: 1.1220x; 1.0073x over previous
//
#include <hip/hip_runtime.h>
#include <hip/hip_bf16.h>
#include <cstdint>

#define DEV __device__ __forceinline__

typedef __bf16 bf16_t;
typedef bf16_t bf16x8 __attribute__((ext_vector_type(8)));
typedef float  f32x4  __attribute__((ext_vector_type(4)));

static constexpr int B_ = 8, T_ = 1024, S_ = 1024, D_ = 512, H_ = 8, F_ = 2048;

typedef const __attribute__((address_space(1))) void* gas_ptr;
typedef __attribute__((address_space(3))) void* las_ptr;

DEV void gload_lds16(const void* g, void* l) {
  __builtin_amdgcn_global_load_lds((gas_ptr)g, (las_ptr)l, 16, 0, 0);
}

// ---------------------------------------------------------------------------
// bf16 GEMM:  C[z] = A[z] (M x K, row-major) * BT[z]^T  (BT is N x K row-major)
// Proven config (R10/R15): BM = MI*32 (MI=2 -> 64), BN = 128. 48 KB LDS double
// buffer, 3 blocks/CU. Counted-vmcnt (steady vmcnt(6)) + raw barriers +
// T2 XOR-swizzle (pre-swizzled global source + swizzled ds_read) +
// T5 setprio + T1 bijective XCD swizzle.
// EPI 0:+bias | 1:+bias,relu | 2:*scale+pad+subsq | 3: accumulate fp32
// causal: 0=none, 2=fully-masked blocks write NOTHING (softmax zero-fill)
// kcap: causal K-limit (rows m0.. need K < m0+BM only)
// ---------------------------------------------------------------------------
template<typename OutT, int EPI, int MI>
__global__ __launch_bounds__(256, (MI == 2) ? 3 : 2) void gemm_bt(
    const bf16_t* __restrict__ A,  int64_t aH, int64_t aB, int lda,
    const bf16_t* __restrict__ BT, int64_t bH, int64_t bB, int ldb,
    OutT* __restrict__ C,          int64_t cH, int64_t cB, int ldo,
    int K, int ZB,
    const float* __restrict__ bias, int64_t biasH, int64_t biasB,
    float scale,
    const float* __restrict__ pad, int64_t padB,
    const float* __restrict__ subsq, int subsq_ld, int causal,
    int initC, int kcap)
{
  constexpr int BM = MI * 32;          // 64 or 128

  // ---- bijective XCD-chunked swizzle over the flattened grid (m204)
  const unsigned gx = gridDim.x, gy = gridDim.y;
  const unsigned nwg = gx * gy * gridDim.z;
  const unsigned orig = (blockIdx.z * gy + blockIdx.y) * gx + blockIdx.x;
  const unsigned q8 = nwg >> 3, r8 = nwg & 7;
  const unsigned xcd = orig & 7, cidx = orig >> 3;
  const unsigned swz = (xcd < r8 ? xcd * (q8 + 1)
                                 : r8 * (q8 + 1) + (xcd - r8) * q8) + cidx;
  const unsigned bz = swz / (gx * gy);
  const unsigned rm = swz - bz * gx * gy;
  const unsigned by = rm / gx;
  const unsigned bx = rm - by * gx;

  const int z  = bz;
  const int zh = z / ZB, zb = z - zh * ZB;
  A  += zh * aH + zb * aB;
  BT += zh * bH + zb * bB;
  C  += zh * cH + zb * cB;
  const int m0 = by * BM;
  const int n0 = bx << 7;

  // fully-masked causal block
  const bool skip = (EPI == 2) && causal && (n0 >= m0 + BM);
  if (skip && causal == 2) return;     // write nothing; nobody reads it

  __shared__ __align__(16) bf16_t As[2][BM * 64];
  __shared__ __align__(16) bf16_t Bs[2][128 * 64];

  const int tid  = threadIdx.x;
  const int lane = tid & 63;
  const int wr   = tid >> 7;          // wave row (0..1)
  const int wc   = (tid >> 6) & 1;    // wave col (0..1)

  f32x4 acc[MI][4] = {};

  int Klim = K;
  if (kcap) { const int lim = m0 + BM; Klim = lim < K ? lim : K; }

  // stage with pre-swizzled global column: LDS slot (row, s) <- global granule
  // (row, s ^ (row&7)); reader XORs the same way -> conflict-free ds_read_b128
  auto stage = [&](int buf, int kb) {
    #pragma unroll
    for (int i = 0; i < MI; ++i) {     // A: BM*64 elems = MI chunks/thread
      const int c = i * 256 + tid;
      const int row = c >> 3;
      const int col = (((c & 7) ^ (row & 7)) << 3);
      gload_lds16(A + (int64_t)(m0 + row) * lda + kb + col, &As[buf][c * 8]);
    }
    #pragma unroll
    for (int i = 0; i < 4; ++i) {      // B: 128*64 elems = 4 chunks/thread
      const int c = i * 256 + tid;
      const int row = c >> 3;
      const int col = (((c & 7) ^ (row & 7)) << 3);
      gload_lds16(BT + (int64_t)(n0 + row) * ldb + kb + col, &Bs[buf][c * 8]);
    }
  };

  if (!skip) {
    const int NT = Klim >> 6;
    stage(0, 0);
    if (NT > 1) stage(1, 64);
    const int hi = lane >> 4, r7 = lane & 7;
    for (int t = 0; t < NT; ++t) {
      // wait tile t complete; tile t+1 (MI+4 loads/thread) stays in flight
      if (t + 1 < NT) {
        if constexpr (MI == 2) asm volatile("s_waitcnt vmcnt(6)" ::: "memory");
        else                   asm volatile("s_waitcnt vmcnt(8)" ::: "memory");
      } else {
        asm volatile("s_waitcnt vmcnt(0)" ::: "memory");
      }
      __builtin_amdgcn_s_barrier();              // raw: no implicit drain
      __builtin_amdgcn_sched_barrier(0);
      const int cur = t & 1;
      // pre-read ALL fragments of tile t (buffer gets overwritten below)
      bf16x8 af[MI][2], bq[4][2];
      #pragma unroll
      for (int ks = 0; ks < 2; ++ks) {
        #pragma unroll
        for (int i = 0; i < MI; ++i)
          af[i][ks] = *(const bf16x8*)&As[cur][(wr * (MI * 16) + i * 16 + (lane & 15)) * 64 + (((ks * 4 + hi) ^ r7) << 3)];
        #pragma unroll
        for (int i = 0; i < 4; ++i)
          bq[i][ks] = *(const bf16x8*)&Bs[cur][(wc * 64 + i * 16 + (lane & 15)) * 64 + (((ks * 4 + hi) ^ r7) << 3)];
      }
      asm volatile("s_waitcnt lgkmcnt(0)" ::: "memory");
      __builtin_amdgcn_sched_barrier(0);
      __builtin_amdgcn_s_barrier();              // all waves done reading buf
      if (t + 2 < NT) stage(cur, (t + 2) << 6);  // restage freed buffer early
      __builtin_amdgcn_sched_barrier(0);         // keep MFMAs after stage issue
      __builtin_amdgcn_s_setprio(1);
      #pragma unroll
      for (int ks = 0; ks < 2; ++ks)
        #pragma unroll
        for (int mi = 0; mi < MI; ++mi)
          #pragma unroll
          for (int ni = 0; ni < 4; ++ni)
            acc[mi][ni] = __builtin_amdgcn_mfma_f32_16x16x32_bf16(af[mi][ks], bq[ni][ks], acc[mi][ni], 0, 0, 0);
      __builtin_amdgcn_s_setprio(0);
    }
  }

  // epilogue; C/D frag layout: col = lane&15, row = 4*(lane>>4)+r
  const float* bz_ = (EPI != 2 && bias) ? bias + zh * biasH + zb * biasB : nullptr;
  const float* pz  = (EPI == 2 && pad)  ? pad + zb * padB : nullptr;
  #pragma unroll
  for (int ni = 0; ni < 4; ++ni) {
    const int col = n0 + wc * 64 + ni * 16 + (lane & 15);
    const float badd = bz_ ? bz_[col] : 0.f;
    const float pv   = pz ? pz[col] : 0.f;
    #pragma unroll
    for (int mi = 0; mi < MI; ++mi) {
      const int rowb = m0 + wr * (MI * 16) + mi * 16 + ((lane >> 4) << 2);
      #pragma unroll
      for (int r = 0; r < 4; ++r) {
        const int row = rowb + r;
        const int64_t idx = (int64_t)row * ldo + col;
        float v = acc[mi][ni][r];
        if (EPI == 2) {
          v = v * scale + pv;
          if (subsq) v += subsq[(int64_t)row * subsq_ld + col];
        } else if (EPI == 3) {
          v += initC ? badd : (float)C[idx];
        } else {
          v += badd;
          if (EPI == 1) v = fmaxf(v, 0.f);
        }
        if constexpr (sizeof(OutT) == 2) C[idx] = (OutT)v;
        else                             C[idx] = v;
      }
    }
  }
}

// ---------------------------------------------------------------------------
// In-place row softmax over 1024 bf16 logits. One block (256 thr) per row.
// CAUSAL=1: row length = (blockIdx % T)+1; reads only the causal prefix,
// zero-fills up to the next multiple of 64 (what PV's kcap reads).
// ---------------------------------------------------------------------------
template<int CAUSAL>
__global__ __launch_bounds__(256) void softmax1024b(bf16_t* __restrict__ P)
{
  const int64_t row = blockIdx.x;
  const int len = CAUSAL ? (int)(row % T_) + 1 : 1024;
  const int tid = threadIdx.x;
  const int j4 = tid << 2;
  float v0 = -3e38f, v1 = -3e38f, v2 = -3e38f, v3 = -3e38f;
  if (j4 < len) {
    union { bf16_t b[4]; uint2 u; } in;
    in.u = ((const uint2*)(P + row * 1024))[tid];
    v0 = (float)in.b[0];
    if (j4 + 1 < len) v1 = (float)in.b[1];
    if (j4 + 2 < len) v2 = (float)in.b[2];
    if (j4 + 3 < len) v3 = (float)in.b[3];
  }
  float m = fmaxf(fmaxf(v0, v1), fmaxf(v2, v3));
  #pragma unroll
  for (int off = 32; off; off >>= 1) m = fmaxf(m, __shfl_xor(m, off));
  __shared__ float red[8];
  if ((tid & 63) == 0) red[tid >> 6] = m;
  __syncthreads();
  m = fmaxf(fmaxf(red[0], red[1]), fmaxf(red[2], red[3]));
  const float e0 = (j4     < len) ? __expf(v0 - m) : 0.f;
  const float e1 = (j4 + 1 < len) ? __expf(v1 - m) : 0.f;
  const float e2 = (j4 + 2 < len) ? __expf(v2 - m) : 0.f;
  const float e3 = (j4 + 3 < len) ? __expf(v3 - m) : 0.f;
  float s = e0 + e1 + e2 + e3;
  #pragma unroll
  for (int off = 32; off; off >>= 1) s += __shfl_xor(s, off);
  if ((tid & 63) == 0) red[4 + (tid >> 6)] = s;
  __syncthreads();
  const float inv = 1.f / (red[4] + red[5] + red[6] + red[7]);
  const int lenc = CAUSAL ? ((len + 63) & ~63) : 1024;  // PV reads < ceil64(len)
  if (j4 < lenc) {
    union { bf16_t b[4]; uint2 u; } o;
    o.b[0] = (bf16_t)(e0 * inv); o.b[1] = (bf16_t)(e1 * inv);
    o.b[2] = (bf16_t)(e2 * inv); o.b[3] = (bf16_t)(e3 * inv);
    ((uint2*)(P + row * 1024))[tid] = o.u;
  }
}

// ---------------------------------------------------------------------------
// y = LayerNorm(a + r) * g + b ; yf fp32 (may alias a or r: element-local),
// yb bf16 (nullable). D=512, block 128.
// ---------------------------------------------------------------------------
__global__ __launch_bounds__(128) void add_ln512(
    const float* __restrict__ a, const float* __restrict__ r,
    const float* __restrict__ g, const float* __restrict__ be,
    float* __restrict__ yf, bf16_t* __restrict__ yb)
{
  const int64_t row = blockIdx.x;
  const int tid = threadIdx.x;
  const float4 va = ((const float4*)(a + row * 512))[tid];
  const float4 vr = ((const float4*)(r + row * 512))[tid];
  const float x0 = va.x + vr.x, x1 = va.y + vr.y, x2 = va.z + vr.z, x3 = va.w + vr.w;
  float s = x0 + x1 + x2 + x3;
  float q = x0 * x0 + x1 * x1 + x2 * x2 + x3 * x3;
  #pragma unroll
  for (int off = 32; off; off >>= 1) { s += __shfl_xor(s, off); q += __shfl_xor(q, off); }
  __shared__ float red[4];
  if ((tid & 63) == 0) { red[tid >> 6] = s; red[2 + (tid >> 6)] = q; }
  __syncthreads();
  s = red[0] + red[1]; q = red[2] + red[3];
  const float mean = s * (1.f / 512.f);
  const float var  = q * (1.f / 512.f) - mean * mean;
  const float rstd = rsqrtf(var + 1e-5f);
  const float4 g4 = ((const float4*)g)[tid];
  const float4 b4 = ((const float4*)be)[tid];
  const float y0 = (x0 - mean) * rstd * g4.x + b4.x;
  const float y1 = (x1 - mean) * rstd * g4.y + b4.y;
  const float y2 = (x2 - mean) * rstd * g4.z + b4.z;
  const float y3 = (x3 - mean) * rstd * g4.w + b4.w;
  float4 o; o.x = y0; o.y = y1; o.z = y2; o.w = y3;
  ((float4*)(yf + row * 512))[tid] = o;
  if (yb) {
    union { bf16_t b[4]; uint2 u; } ob;
    ob.b[0] = (bf16_t)y0; ob.b[1] = (bf16_t)y1; ob.b[2] = (bf16_t)y2; ob.b[3] = (bf16_t)y3;
    ((uint2*)(yb + row * 512))[tid] = ob.u;
  }
}

// ---------------------------------------------------------------------------
// Transpose + cast: src [z][R][C] (InT) -> dst [z][C][R] (bf16)
// ---------------------------------------------------------------------------
template<typename InT>
__global__ __launch_bounds__(256) void tcast(
    const InT* __restrict__ src, bf16_t* __restrict__ dst, int R, int C)
{
  __shared__ float t[32][33];
  const int64_t zo = (int64_t)blockIdx.z * R * C;
  const int c0 = blockIdx.x << 5, r0 = blockIdx.y << 5;
  const int tx = threadIdx.x & 31, ty = threadIdx.x >> 5;
  #pragma unroll
  for (int i = 0; i < 32; i += 8)
    t[ty + i][tx] = (float)src[zo + (int64_t)(r0 + ty + i) * C + c0 + tx];
  __syncthreads();
  #pragma unroll
  for (int i = 0; i < 32; i += 8)
    dst[zo + (int64_t)(c0 + ty + i) * R + r0 + tx] = (bf16_t)t[tx][ty + i];
}

// Fused: all 4*H D x D weight transposes in one dispatch.
// z in [0,32): set = z>>3 (0:Wq 1:Wk 2:Wv 3:Wqm), h = z&7.
__global__ __launch_bounds__(256) void tcastW(
    const float* __restrict__ Wq, const float* __restrict__ Wk,
    const float* __restrict__ Wv, const float* __restrict__ Wqm,
    bf16_t* __restrict__ WTqkv, bf16_t* __restrict__ WqmT)
{
  __shared__ float t[32][33];
  const int zz = blockIdx.z, set = zz >> 3, h = zz & 7;
  const int64_t DD = (int64_t)D_ * D_;
  const float* src = (set == 0 ? Wq : set == 1 ? Wk : set == 2 ? Wv : Wqm) + (int64_t)h * DD;
  bf16_t* dst = (set < 3) ? WTqkv + (int64_t)(set * H_ + h) * DD
                          : WqmT + (int64_t)h * DD;
  const int c0 = blockIdx.x << 5, r0 = blockIdx.y << 5;
  const int tx = threadIdx.x & 31, ty = threadIdx.x >> 5;
  #pragma unroll
  for (int i = 0; i < 32; i += 8)
    t[ty + i][tx] = src[(int64_t)(r0 + ty + i) * D_ + c0 + tx];
  __syncthreads();
  #pragma unroll
  for (int i = 0; i < 32; i += 8)
    dst[(int64_t)(c0 + ty + i) * D_ + r0 + tx] = (bf16_t)t[tx][ty + i];
}

// Fused: Wo and Wom ([H*D][D] -> [D][H*D]) in one dispatch (z = 0/1).
__global__ __launch_bounds__(256) void tcastO(
    const float* __restrict__ Wo, const float* __restrict__ Wom,
    bf16_t* __restrict__ WoT, bf16_t* __restrict__ WomT)
{
  __shared__ float t[32][33];
  const int which = blockIdx.z;
  const float* src = which ? Wom : Wo;
  bf16_t* dst = which ? WomT : WoT;
  const int R = H_ * D_, C = D_;
  const int c0 = blockIdx.x << 5, r0 = blockIdx.y << 5;
  const int tx = threadIdx.x & 31, ty = threadIdx.x >> 5;
  #pragma unroll
  for (int i = 0; i < 32; i += 8)
    t[ty + i][tx] = src[(int64_t)(r0 + ty + i) * C + c0 + tx];
  __syncthreads();
  #pragma unroll
  for (int i = 0; i < 32; i += 8)
    dst[(int64_t)(c0 + ty + i) * R + r0 + tx] = (bf16_t)t[tx][ty + i];
}

// Fused: two fp32->bf16 casts in one dispatch (z = 0/1).
__global__ __launch_bounds__(256) void castf2b2(
    const float* __restrict__ s0, bf16_t* __restrict__ d0,
    const float* __restrict__ s1, bf16_t* __restrict__ d1, int n4)
{
  const int i = blockIdx.x * 256 + threadIdx.x;
  if (i >= n4) return;
  const float* s = blockIdx.z ? s1 : s0;
  bf16_t* d = blockIdx.z ? d1 : d0;
  const float4 v = ((const float4*)s)[i];
  union { bf16_t b[4]; uint2 u; } o;
  o.b[0] = (bf16_t)v.x; o.b[1] = (bf16_t)v.y; o.b[2] = (bf16_t)v.z; o.b[3] = (bf16_t)v.w;
  ((uint2*)d)[i] = o.u;
}

__global__ __launch_bounds__(256) void pack3(
    const float* __restrict__ a, const float* __restrict__ b,
    const float* __restrict__ c, float* __restrict__ d, int n)
{
  const int i = blockIdx.x * 256 + threadIdx.x;
  if (i < n) { d[i] = a[i]; d[n + i] = b[i]; d[2 * n + i] = c[i]; }
}

// ---------------------------------------------------------------------------
extern "C" void kernel_launch(void* const* d_in, const int* in_sizes, int n_in,
                              void* d_out, int out_size, void* d_ws, size_t ws_size,
                              hipStream_t stream)
{
  const float* x       = (const float*)d_in[0];
  const float* src_pad = (const float*)d_in[1];
  const float* tgt_pad = (const float*)d_in[3];
  const float* tgt_sub = (const float*)d_in[4];
  const float* mk      = (const float*)d_in[5];
  const float* mv      = (const float*)d_in[6];
  const float* Wq  = (const float*)d_in[7];
  const float* bq  = (const float*)d_in[8];
  const float* Wk  = (const float*)d_in[9];
  const float* bk  = (const float*)d_in[10];
  const float* Wv  = (const float*)d_in[11];
  const float* bv  = (const float*)d_in[12];
  const float* Wo  = (const float*)d_in[13];
  const float* bo  = (const float*)d_in[14];
  const float* Wqm = (const float*)d_in[15];
  const float* bqm = (const float*)d_in[16];
  const float* Wom = (const float*)d_in[17];
  const float* bom = (const float*)d_in[18];
  const float* W1  = (const float*)d_in[19];
  const float* b1  = (const float*)d_in[20];
  const float* W2  = (const float*)d_in[21];
  const float* b2  = (const float*)d_in[22];
  const float* g1  = (const float*)d_in[23];
  const float* be1 = (const float*)d_in[24];
  const float* g2  = (const float*)d_in[25];
  const float* be2 = (const float*)d_in[26];
  const float* g3  = (const float*)d_in[27];
  const float* be3 = (const float*)d_in[28];
  float* outf = (float*)d_out;   // fp32 projection target / final out

  constexpr int64_t BTD = (int64_t)B_ * T_ * D_;  // 4 Mi elements
  constexpr int64_t BTS = (int64_t)B_ * T_ * S_;  // 8 Mi elements
  constexpr int64_t DD  = (int64_t)D_ * D_;
  const int M8 = B_ * T_;                          // 8192

  char* p = (char*)d_ws;
  auto alloc = [&](int64_t bytes) -> void* {
    char* r = p; p += (bytes + 255) & ~(int64_t)255; return (void*)r;
  };
  // ---- persistent (~68 MiB)
  bf16_t* WTqkv = (bf16_t*)alloc(3 * H_ * DD * 2);            // [3][H][D][D]
  bf16_t* WoT   = (bf16_t*)alloc((int64_t)D_ * H_ * D_ * 2);  // [512][4096]
  bf16_t* WqmT  = (bf16_t*)alloc(H_ * DD * 2);                // [H][D][D]
  bf16_t* WomT  = (bf16_t*)alloc((int64_t)D_ * H_ * D_ * 2);  // [512][4096]
  bf16_t* W1T   = (bf16_t*)alloc((int64_t)F_ * D_ * 2);       // [2048][512]
  bf16_t* W2T   = (bf16_t*)alloc((int64_t)D_ * F_ * 2);       // [512][2048]
  float*  bqkv  = (float*)alloc(3 * H_ * D_ * 4);
  bf16_t* actb  = (bf16_t*)alloc(BTD * 2);                    // xb -> x1b -> x2b
  bf16_t* mkb   = (bf16_t*)alloc(BTD * 2);
  bf16_t* mvT   = (bf16_t*)alloc(BTD * 2);                    // [B][D][S]
  float*  x1f   = (float*)alloc(BTD * 4);                     // x1 -> x2 (in-place)

  const int64_t remain = (int64_t)ws_size - (int64_t)(p - (char*)d_ws);
  const int64_t perG   = 3 * BTD * 2 + BTD * 2 + BTS * 2;     // qkv+vt+logit per head
  const int64_t hoCat  = (int64_t)B_ * T_ * H_ * D_ * 2;      // cat layout [B][T][H*D]
  int G = 0;
  for (int g = 8; g >= 1; g >>= 1)
    if (remain >= hoCat + (int64_t)g * perG + (4 << 20)) { G = g; break; }
  const int64_t needB = 3 * BTD * 2 + BTD * 2 + BTS * 2 + BTD * 2 + (1 << 20);
  if (G == 0 && remain < needB) return;  // clean failure: ws too small

  const float scale = 1.0f / sqrtf((float)D_);
  dim3 blk(256);

  // ---- prologue (fused: 7 dispatches instead of 12)
  castf2b2<<<dim3((unsigned)(BTD / 4 / 256), 1, 2), blk, 0, stream>>>(
      x, actb, mk, mkb, (int)(BTD / 4));
  tcast<float><<<dim3(D_ / 32, S_ / 32, B_), blk, 0, stream>>>(mv, mvT, S_, D_);
  tcastW<<<dim3(D_ / 32, D_ / 32, 32), blk, 0, stream>>>(Wq, Wk, Wv, Wqm, WTqkv, WqmT);
  tcastO<<<dim3(D_ / 32, (H_ * D_) / 32, 2), blk, 0, stream>>>(Wo, Wom, WoT, WomT);
  tcast<float><<<dim3(F_ / 32, D_ / 32, 1), blk, 0, stream>>>(W1, W1T, D_, F_);
  tcast<float><<<dim3(D_ / 32, F_ / 32, 1), blk, 0, stream>>>(W2, W2T, F_, D_);
  pack3<<<dim3((H_ * D_ + 255) / 256), blk, 0, stream>>>(bq, bk, bv, bqkv, H_ * D_);

  bf16_t* ffh = nullptr;  // [8192][2048] alias set per path

  if (G > 0) {
    // =========== Path A: head-group batching, cat-layout ho ===========
    bf16_t* hoAll = (bf16_t*)alloc(hoCat);                    // [B][T][H*D]
    bf16_t* qkv   = (bf16_t*)alloc(3 * G * BTD * 2);          // [3][G][B][T][D]
    bf16_t* vt    = (bf16_t*)alloc((int64_t)G * BTD * 2);     // [G*B][D][T]
    bf16_t* logit = (bf16_t*)alloc((int64_t)G * BTS * 2);     // [G][B][T][S]
    ffh = qkv;

    // ---- self-attention
    for (int h0 = 0; h0 < H_; h0 += G) {
      gemm_bt<bf16_t, 0, 2><<<dim3(D_ / 128, M8 / 64, 3 * G), blk, 0, stream>>>(
          actb, 0, 0, D_,
          WTqkv + (int64_t)h0 * DD, (int64_t)H_ * DD, DD, D_,
          qkv, (int64_t)G * BTD, BTD, D_,
          D_, G,
          bqkv + h0 * D_, (int64_t)H_ * D_, D_,
          1.f, nullptr, 0, nullptr, 0, 0, 0, 0);
      tcast<bf16_t><<<dim3(D_ / 32, T_ / 32, G * B_), blk, 0, stream>>>(
          qkv + (int64_t)2 * G * BTD, vt, T_, D_);
      gemm_bt<bf16_t, 2, 2><<<dim3(S_ / 128, T_ / 64, G * B_), blk, 0, stream>>>(
          qkv, BTD, (int64_t)T_ * D_, D_,
          qkv + (int64_t)G * BTD, BTD, (int64_t)T_ * D_, D_,
          logit, BTS, (int64_t)T_ * S_, S_,
          D_, B_,
          nullptr, 0, 0,
          scale, tgt_pad, T_, tgt_sub, S_, /*causal=*/2, 0, 0);
      softmax1024b<1><<<dim3((unsigned)(G * B_ * T_)), blk, 0, stream>>>(logit);
      gemm_bt<bf16_t, 0, 2><<<dim3(D_ / 128, T_ / 64, G * B_), blk, 0, stream>>>(
          logit, BTS, (int64_t)T_ * S_, S_,
          vt, (int64_t)B_ * D_ * T_, (int64_t)D_ * T_, T_,
          hoAll + (int64_t)h0 * D_, D_, (int64_t)T_ * H_ * D_, H_ * D_,
          S_, B_,
          nullptr, 0, 0, 1.f, nullptr, 0, nullptr, 0, 0, 0, /*kcap=*/1);
    }
    gemm_bt<float, 0, 2><<<dim3(D_ / 128, M8 / 64, 1), blk, 0, stream>>>(
        hoAll, 0, 0, H_ * D_, WoT, 0, 0, H_ * D_, outf, 0, 0, D_,
        H_ * D_, 1, bo, 0, 0, 1.f, nullptr, 0, nullptr, 0, 0, 0, 0);
    add_ln512<<<dim3(M8), dim3(128), 0, stream>>>(outf, x, g1, be1, x1f, actb);

    // ---- cross-attention
    for (int h0 = 0; h0 < H_; h0 += G) {
      gemm_bt<bf16_t, 0, 2><<<dim3(D_ / 128, M8 / 64, G), blk, 0, stream>>>(
          actb, 0, 0, D_,
          WqmT + (int64_t)h0 * DD, 0, DD, D_,
          qkv, 0, BTD, D_,
          D_, G,
          bqm + h0 * D_, 0, D_,
          1.f, nullptr, 0, nullptr, 0, 0, 0, 0);
      gemm_bt<bf16_t, 2, 2><<<dim3(S_ / 128, T_ / 64, G * B_), blk, 0, stream>>>(
          qkv, BTD, (int64_t)T_ * D_, D_,
          mkb, 0, (int64_t)S_ * D_, D_,
          logit, BTS, (int64_t)T_ * S_, S_,
          D_, B_,
          nullptr, 0, 0,
          scale, src_pad, S_, nullptr, 0, 0, 0, 0);
      softmax1024b<0><<<dim3((unsigned)(G * B_ * T_)), blk, 0, stream>>>(logit);
      gemm_bt<bf16_t, 0, 2><<<dim3(D_ / 128, T_ / 64, G * B_), blk, 0, stream>>>(
          logit, BTS, (int64_t)T_ * S_, S_,
          mvT, 0, (int64_t)D_ * S_, S_,
          hoAll + (int64_t)h0 * D_, D_, (int64_t)T_ * H_ * D_, H_ * D_,
          S_, B_,
          nullptr, 0, 0, 1.f, nullptr, 0, nullptr, 0, 0, 0, 0);
    }
    gemm_bt<float, 0, 2><<<dim3(D_ / 128, M8 / 64, 1), blk, 0, stream>>>(
        hoAll, 0, 0, H_ * D_, WomT, 0, 0, H_ * D_, outf, 0, 0, D_,
        H_ * D_, 1, bom, 0, 0, 1.f, nullptr, 0, nullptr, 0, 0, 0, 0);
    add_ln512<<<dim3(M8), dim3(128), 0, stream>>>(outf, x1f, g2, be2, x1f, actb);
  } else {
    // =========== Path B: per-head with accumulate out-proj ===========
    bf16_t* qkvH  = (bf16_t*)alloc(3 * BTD * 2);
    bf16_t* vtH   = (bf16_t*)alloc(BTD * 2);
    bf16_t* logit = (bf16_t*)alloc(BTS * 2);
    bf16_t* hoH   = (bf16_t*)alloc(BTD * 2);
    ffh = qkvH;

    for (int h = 0; h < H_; ++h) {
      gemm_bt<bf16_t, 0, 2><<<dim3(D_ / 128, M8 / 64, 3), blk, 0, stream>>>(
          actb, 0, 0, D_,
          WTqkv + (int64_t)h * DD, (int64_t)H_ * DD, 0, D_,
          qkvH, BTD, 0, D_,
          D_, 1,
          bqkv + h * D_, (int64_t)H_ * D_, 0,
          1.f, nullptr, 0, nullptr, 0, 0, 0, 0);
      tcast<bf16_t><<<dim3(D_ / 32, T_ / 32, B_), blk, 0, stream>>>(
          qkvH + 2 * BTD, vtH, T_, D_);
      gemm_bt<bf16_t, 2, 2><<<dim3(S_ / 128, T_ / 64, B_), blk, 0, stream>>>(
          qkvH, 0, (int64_t)T_ * D_, D_,
          qkvH + BTD, 0, (int64_t)T_ * D_, D_,
          logit, 0, (int64_t)T_ * S_, S_,
          D_, B_,
          nullptr, 0, 0,
          scale, tgt_pad, T_, tgt_sub, S_, 2, 0, 0);
      softmax1024b<1><<<dim3((unsigned)(B_ * T_)), blk, 0, stream>>>(logit);
      gemm_bt<bf16_t, 0, 2><<<dim3(D_ / 128, T_ / 64, B_), blk, 0, stream>>>(
          logit, 0, (int64_t)T_ * S_, S_,
          vtH, 0, (int64_t)D_ * T_, T_,
          hoH, 0, (int64_t)T_ * D_, D_,
          S_, B_,
          nullptr, 0, 0, 1.f, nullptr, 0, nullptr, 0, 0, 0, /*kcap=*/1);
      gemm_bt<float, 3, 2><<<dim3(D_ / 128, M8 / 64, 1), blk, 0, stream>>>(
          hoH, 0, 0, D_,
          WoT + (int64_t)h * D_, 0, 0, H_ * D_,
          outf, 0, 0, D_,
          D_, 1,
          bo, 0, 0, 1.f, nullptr, 0, nullptr, 0, 0, (h == 0) ? 1 : 0, 0);
    }
    add_ln512<<<dim3(M8), dim3(128), 0, stream>>>(outf, x, g1, be1, x1f, actb);

    for (int h = 0; h < H_; ++h) {
      gemm_bt<bf16_t, 0, 2><<<dim3(D_ / 128, M8 / 64, 1), blk, 0, stream>>>(
          actb, 0, 0, D_,
          WqmT + (int64_t)h * DD, 0, 0, D_,
          qkvH, 0, 0, D_,
          D_, 1,
          bqm + h * D_, 0, 0,
          1.f, nullptr, 0, nullptr, 0, 0, 0, 0);
      gemm_bt<bf16_t, 2, 2><<<dim3(S_ / 128, T_ / 64, B_), blk, 0, stream>>>(
          qkvH, 0, (int64_t)T_ * D_, D_,
          mkb, 0, (int64_t)S_ * D_, D_,
          logit, 0, (int64_t)T_ * S_, S_,
          D_, B_,
          nullptr, 0, 0,
          scale, src_pad, S_, nullptr, 0, 0, 0, 0);
      softmax1024b<0><<<dim3((unsigned)(B_ * T_)), blk, 0, stream>>>(logit);
      gemm_bt<bf16_t, 0, 2><<<dim3(D_ / 128, T_ / 64, B_), blk, 0, stream>>>(
          logit, 0, (int64_t)T_ * S_, S_,
          mvT, 0, (int64_t)D_ * S_, S_,
          hoH, 0, (int64_t)T_ * D_, D_,
          S_, B_,
          nullptr, 0, 0, 1.f, nullptr, 0, nullptr, 0, 0, 0, 0);
      gemm_bt<float, 3, 2><<<dim3(D_ / 128, M8 / 64, 1), blk, 0, stream>>>(
          hoH, 0, 0, D_,
          WomT + (int64_t)h * D_, 0, 0, H_ * D_,
          outf, 0, 0, D_,
          D_, 1,
          bom, 0, 0, 1.f, nullptr, 0, nullptr, 0, 0, (h == 0) ? 1 : 0, 0);
    }
    add_ln512<<<dim3(M8), dim3(128), 0, stream>>>(outf, x1f, g2, be2, x1f, actb);
  }

  // ---- FFN (common)
  gemm_bt<bf16_t, 1, 2><<<dim3(F_ / 128, M8 / 64, 1), blk, 0, stream>>>(
      actb, 0, 0, D_, W1T, 0, 0, D_, ffh, 0, 0, F_,
      D_, 1, b1, 0, 0, 1.f, nullptr, 0, nullptr, 0, 0, 0, 0);
  gemm_bt<float, 0, 2><<<dim3(D_ / 128, M8 / 64, 1), blk, 0, stream>>>(
      ffh, 0, 0, F_, W2T, 0, 0, F_, outf, 0, 0, D_,
      F_, 1, b2, 0, 0, 1.f, nullptr, 0, nullptr, 0, 0, 0, 0);
  add_ln512<<<dim3(M8), dim3(128), 0, stream>>>(outf, x1f, g3, be3, outf, nullptr);

  (void)in_sizes; (void)n_in; (void)out_size;
}